// Round 1
// baseline (483.337 us; speedup 1.0000x reference)
//
#include <hip/hip_runtime.h>

#define LL 2048
#define DD 128
#define NBATCH 32
#define SCALE 0.08838834764831845f

typedef short short8 __attribute__((ext_vector_type(8)));
typedef short short4v __attribute__((ext_vector_type(4)));
typedef float f32x4 __attribute__((ext_vector_type(4)));

__device__ __forceinline__ unsigned short f2bf(float f) {
  unsigned int u = __float_as_uint(f);
  u += 0x7fffu + ((u >> 16) & 1u);   // round-to-nearest-even
  return (unsigned short)(u >> 16);
}

__global__ __launch_bounds__(256) void attn_fused(
    const float* __restrict__ q, const float* __restrict__ k,
    const float* __restrict__ v, float* __restrict__ out) {
  __shared__ __align__(16) unsigned short kT[32 * 128];   // K chunk, XOR-swizzled
  __shared__ __align__(16) unsigned short vT[128 * 40];   // V chunk transposed, padded
  __shared__ __align__(16) unsigned short pb[4][16 * 32]; // per-wave P staging

  const int tid = threadIdx.x;
  const int w   = tid >> 6;
  const int l   = tid & 63;
  const int lg  = l >> 4;    // lane group 0..3
  const int lr  = l & 15;    // lane row 0..15
  const int b   = blockIdx.y;
  const int q0  = blockIdx.x * 64 + w * 16;

  const float* qb = q + (size_t)b * LL * DD;
  const float* kb = k + (size_t)b * LL * DD;
  const float* vb = v + (size_t)b * LL * DD;
  float* ctx  = out + ((size_t)b * LL + q0) * DD;
  float* attn = out + (size_t)NBATCH * LL * DD + ((size_t)b * LL + q0) * (size_t)LL;

  // ---- load Q fragments (A operand): lane holds Q[q0+lr][dt*32 + lg*8 + j] ----
  short8 aq[4];
  {
    const float* qrow = qb + (size_t)(q0 + lr) * DD + lg * 8;
#pragma unroll
    for (int dt = 0; dt < 4; ++dt) {
      f32x4 x0 = *(const f32x4*)(qrow + dt * 32);
      f32x4 x1 = *(const f32x4*)(qrow + dt * 32 + 4);
      short8 a;
#pragma unroll
      for (int j = 0; j < 4; ++j) {
        a[j]     = (short)f2bf(x0[j]);
        a[4 + j] = (short)f2bf(x1[j]);
      }
      aq[dt] = a;
    }
  }

  float lsum[4] = {0.f, 0.f, 0.f, 0.f};

  // =================== pass 1: softmax denominators ===================
  for (int kc = 0; kc < LL / 32; ++kc) {
    __syncthreads();
#pragma unroll
    for (int i = 0; i < 4; ++i) {              // stage K chunk (32x128), coalesced
      int idx = i * 256 + tid;
      int r   = idx >> 5;
      int c4  = idx & 31;
      f32x4 x = *(const f32x4*)(kb + (size_t)(kc * 32 + r) * DD + c4 * 4);
      short4v y;
#pragma unroll
      for (int j = 0; j < 4; ++j) y[j] = (short)f2bf(x[j]);
      *(short4v*)&kT[(r * 128 + c4 * 4) ^ ((r & 7) << 3)] = y;
    }
    __syncthreads();

#pragma unroll
    for (int kt = 0; kt < 2; ++kt) {
      f32x4 acc = {0.f, 0.f, 0.f, 0.f};
#pragma unroll
      for (int dt = 0; dt < 4; ++dt) {
        int row = kt * 16 + lr;
        short8 bk = *(const short8*)&kT[(row * 128 + dt * 32 + lg * 8) ^ ((row & 7) << 3)];
        acc = __builtin_amdgcn_mfma_f32_16x16x32_bf16(aq[dt], bk, acc, 0, 0, 0);
      }
#pragma unroll
      for (int r = 0; r < 4; ++r) lsum[r] += __expf(acc[r] * SCALE);
    }
  }
  // reduce Σexp over the 16-lane key dimension; keep reciprocal
#pragma unroll
  for (int r = 0; r < 4; ++r) {
    float s = lsum[r];
    s += __shfl_xor(s, 1);
    s += __shfl_xor(s, 2);
    s += __shfl_xor(s, 4);
    s += __shfl_xor(s, 8);
    lsum[r] = 1.0f / s;
  }

  f32x4 apv[8];
#pragma unroll
  for (int dt = 0; dt < 8; ++dt) apv[dt] = (f32x4){0.f, 0.f, 0.f, 0.f};

  // =================== pass 2: attn write + PV ===================
  for (int kc = 0; kc < LL / 32; ++kc) {
    __syncthreads();
#pragma unroll
    for (int i = 0; i < 4; ++i) {              // stage K chunk
      int idx = i * 256 + tid;
      int r   = idx >> 5;
      int c4  = idx & 31;
      f32x4 x = *(const f32x4*)(kb + (size_t)(kc * 32 + r) * DD + c4 * 4);
      short4v y;
#pragma unroll
      for (int j = 0; j < 4; ++j) y[j] = (short)f2bf(x[j]);
      *(short4v*)&kT[(r * 128 + c4 * 4) ^ ((r & 7) << 3)] = y;
    }
    {                                          // stage V chunk transposed: vT[d][kk]
      int kr0 = (tid & 7) * 4;
      int c0  = (tid >> 3) * 4;
      f32x4 rv[4];
#pragma unroll
      for (int i = 0; i < 4; ++i)
        rv[i] = *(const f32x4*)(vb + (size_t)(kc * 32 + kr0 + i) * DD + c0);
#pragma unroll
      for (int j = 0; j < 4; ++j) {
        short4v y = {(short)f2bf(rv[0][j]), (short)f2bf(rv[1][j]),
                     (short)f2bf(rv[2][j]), (short)f2bf(rv[3][j])};
        *(short4v*)&vT[(c0 + j) * 40 + kr0] = y;
      }
    }
    __syncthreads();

#pragma unroll
    for (int kt = 0; kt < 2; ++kt) {
      f32x4 acc = {0.f, 0.f, 0.f, 0.f};
#pragma unroll
      for (int dt = 0; dt < 4; ++dt) {
        int row = kt * 16 + lr;
        short8 bk = *(const short8*)&kT[(row * 128 + dt * 32 + lg * 8) ^ ((row & 7) << 3)];
        acc = __builtin_amdgcn_mfma_f32_16x16x32_bf16(aq[dt], bk, acc, 0, 0, 0);
      }
#pragma unroll
      for (int r = 0; r < 4; ++r) {
        float p = __expf(acc[r] * SCALE) * lsum[r];
        int qrow = lg * 4 + r;
        attn[(size_t)qrow * LL + kc * 32 + kt * 16 + lr] = p;
        pb[w][(qrow * 32 + kt * 16 + lr) ^ ((qrow & 3) << 3)] = f2bf(p);
      }
    }

    // PV: A = P (from pb, transposed layout), B = V (from vT)
    short8 ap = *(const short8*)&pb[w][(lr * 32 + lg * 8) ^ ((lr & 3) << 3)];
#pragma unroll
    for (int dt = 0; dt < 8; ++dt) {
      int row = dt * 16 + lr;
      short4v v0 = *(const short4v*)&vT[row * 40 + lg * 8];
      short4v v1 = *(const short4v*)&vT[row * 40 + lg * 8 + 4];
      short8 bv = {v0[0], v0[1], v0[2], v0[3], v1[0], v1[1], v1[2], v1[3]};
      apv[dt] = __builtin_amdgcn_mfma_f32_16x16x32_bf16(ap, bv, apv[dt], 0, 0, 0);
    }
  }

  // ---- store context ----
#pragma unroll
  for (int dt = 0; dt < 8; ++dt)
#pragma unroll
    for (int r = 0; r < 4; ++r)
      ctx[(size_t)(lg * 4 + r) * DD + dt * 16 + lr] = apv[dt][r];
}

extern "C" void kernel_launch(void* const* d_in, const int* in_sizes, int n_in,
                              void* d_out, int out_size, void* d_ws, size_t ws_size,
                              hipStream_t stream) {
  const float* q = (const float*)d_in[0];
  const float* k = (const float*)d_in[1];
  const float* v = (const float*)d_in[2];
  float* out = (float*)d_out;
  dim3 grid(LL / 64, NBATCH);
  dim3 block(256);
  attn_fused<<<grid, block, 0, stream>>>(q, k, v, out);
}